// Round 9
// baseline (186.616 us; speedup 1.0000x reference)
//
#include <hip/hip_runtime.h>

typedef unsigned short u16;
typedef unsigned int   u32;
typedef short bfrag8 __attribute__((ext_vector_type(8)));   // 8 bf16 (raw bits) = 4 VGPRs
typedef float facc4  __attribute__((ext_vector_type(4)));   // MFMA accumulator

#define DIM    1024
#define NH     16
#define HD     64
#define BSZ    4
#define SEQ    2048
#define MROWS  (BSZ*SEQ)      /* 8192 */
#define CHUNK  64
#define NCHUNK (SEQ/CHUNK)    /* 32 */
#define BH     (BSZ*NH)       /* 64 */
#define TS     72             /* transposed-tile LDS row stride (u16) */
#define NT     16             /* K-tiles per GEMM (K=1024, BK=64) */

__device__ __forceinline__ u16 f2bf(float f) {
  u32 u = __builtin_bit_cast(u32, f);
  u32 r = u + 0x7fffu + ((u >> 16) & 1u);   // RNE
  return (u16)(r >> 16);
}
__device__ __forceinline__ float bf2f(u16 b) {
  return __builtin_bit_cast(float, (u32)b << 16);
}

__device__ __forceinline__ void gload_lds16(const void* g, void* l) {
  __builtin_amdgcn_global_load_lds((const __attribute__((address_space(1))) u32*)g,
                                   (__attribute__((address_space(3))) u32*)l, 16, 0, 0);
}

// ---------------- prep kernels ----------------

__global__ __launch_bounds__(256) void conv_f32_bf16(const float* __restrict__ in, u16* __restrict__ out) {
  const int i = (blockIdx.x * 256 + threadIdx.x) * 4;
  const float4 v = *(const float4*)(in + i);
  ushort4 o;
  o.x = f2bf(v.x); o.y = f2bf(v.y); o.z = f2bf(v.z); o.w = f2bf(v.w);
  *(ushort4*)(out + i) = o;
}

// Wq' = Wq @ blockdiag(proj), stored TRANSPOSED bf16: wt[(h*64+e)*DIM + i]
__global__ __launch_bounds__(256) void fold_qk(const float* __restrict__ Wq, const float* __restrict__ Wk,
                                               const float* __restrict__ proj, u16* __restrict__ wt) {
  const int i0 = blockIdx.x * 32;
  const int h  = blockIdx.y;
  const int sel = blockIdx.z;           // 0 -> Wq (slot 0), 1 -> Wk (slot 1)
  const float* W = sel ? Wk : Wq;
  u16* out = wt + (size_t)sel * (DIM*DIM);
  __shared__ float sp[64*64];
  __shared__ float sw[32*64];
  const int tid = threadIdx.x;
  for (int idx = tid; idx < 4096; idx += 256) sp[idx] = proj[idx];
  for (int idx = tid; idx < 2048; idx += 256) {
    int r = idx >> 6, c = idx & 63;
    sw[idx] = W[(size_t)(i0 + r)*DIM + h*64 + c];
  }
  __syncthreads();
  const int i  = tid >> 3;
  const int e0 = (tid & 7) * 8;
  #pragma unroll
  for (int ee = 0; ee < 8; ++ee) {
    const int e = e0 + ee;
    float acc = 0.f;
    for (int d = 0; d < 64; ++d) acc += sw[i*64 + d] * sp[d*64 + e];
    out[(size_t)(h*64 + e)*DIM + i0 + i] = f2bf(acc);
  }
}

// transpose + convert: slot2 = Wv^T, slot3 = Wo^T
__global__ __launch_bounds__(256) void trans_conv(const float* __restrict__ Wv, const float* __restrict__ Wo,
                                                  u16* __restrict__ wt) {
  const int sel = blockIdx.z;
  const float* in = sel ? Wo : Wv;
  u16* out = wt + (size_t)(2 + sel) * (DIM*DIM);
  const int n0 = blockIdx.x * 32, k0 = blockIdx.y * 32;
  __shared__ float tile[32][33];
  const int tid = threadIdx.x;
  for (int idx = tid; idx < 1024; idx += 256) {
    int r = idx >> 5, c = idx & 31;
    tile[r][c] = in[(size_t)(k0 + r)*DIM + n0 + c];
  }
  __syncthreads();
  for (int idx = tid; idx < 1024; idx += 256) {
    int r = idx >> 5, c = idx & 31;
    out[(size_t)(n0 + r)*DIM + k0 + c] = f2bf(tile[c][r]);
  }
}

// ---------- 128x256 kh-split full-read-ahead bf16 MFMA GEMM, C = A @ Wt^T ----------
// Wt is [N][K] row-major bf16. 512 threads = 8 waves (2M x 4N); per-wave C = 64x64.
// BK=64 split into kh=0/1 phases of 16 MFMA each. Two frag sets ping-pong by parity:
//   P0(t): MFMA set A (t,kh0); read set B (t,kh1) from buf p. close: vmcnt(0)+barrier.
//   P1(t): MFMA set B; stage t+2 -> buf p; read set A (t+1,kh0) from buf q. close: barrier.
// Every lgkmcnt(0) waits reads issued one full MFMA-phase earlier (free). The lone
// vmcnt(0) drains stages issued 1.5 phases earlier (window >> latency+L2 service).
// Ledger: buf p's last reads are P0(t)'s (certified by P0-close barrier before P1's
// stage writes arrive); buf q certified by P0-close vmcnt(0)+barrier before P1 reads.
// LDS 2 x (16K X + 32K W) = 96 KB. Swizzle (verified 0-conflict): slot8 = (kh*4+g)^(row&7).
// Operands swapped (W = MFMA A-operand) so lane regs = 4 consecutive output columns.
// MODE 0: QKV fused over wt rows 0..3071 (elu+1 for sel<2; bf16 out); grid 768 = 3 rounds.
// MODE 1: out GEMM (fp32 out); grid 256 = 1 round.

#define SBAR0() __builtin_amdgcn_sched_barrier(0)

// stage tile kt (6 x 8KB units: X seg0-1, W seg0-3) into buffer at base bp (u16*)
#define STAGE6(kt, bp) { \
  const int rih = tid >> 3, sl = tid & 7; \
  const int gc = ((sl ^ (rih & 7)) << 3); \
  _Pragma("unroll") for (int seg = 0; seg < 2; ++seg) \
    gload_lds16(A + (size_t)(m0 + seg*64 + rih)*DIM + (kt)*64 + gc, (bp) + seg*4096 + tid*8); \
  _Pragma("unroll") for (int seg = 0; seg < 4; ++seg) \
    gload_lds16(W + (size_t)(ngl + seg*64 + rih)*DIM + (kt)*64 + gc, (bp) + 8192 + seg*4096 + tid*8); \
}

// read 8 frags (4 X + 4 W) of kh-half KH from buffer bp into xd/wd
#define RD8(xd, wd, bp, KH) { \
  _Pragma("unroll") for (int mf = 0; mf < 4; ++mf) { \
    const int row = wm*64 + mf*16 + lr; \
    xd[mf] = *(const bfrag8*)&(bp)[row*64 + ((((KH)*4+g) ^ (row & 7)) << 3)]; } \
  _Pragma("unroll") for (int nf = 0; nf < 4; ++nf) { \
    const int row = wn*64 + nf*16 + lr; \
    wd[nf] = *(const bfrag8*)&(bp)[8192 + row*64 + ((((KH)*4+g) ^ (row & 7)) << 3)]; } \
}

#define MM16(xs, ws) { __builtin_amdgcn_s_setprio(1); \
  _Pragma("unroll") for (int nf = 0; nf < 4; ++nf) \
    _Pragma("unroll") for (int mf = 0; mf < 4; ++mf) \
      acc[nf][mf] = __builtin_amdgcn_mfma_f32_16x16x32_bf16(ws[nf], xs[mf], acc[nf][mf], 0, 0, 0); \
  __builtin_amdgcn_s_setprio(0); }

template<int MODE>
__global__ __launch_bounds__(512, 1)
void gemmK(const u16* __restrict__ A, const u16* __restrict__ W,
           u16* __restrict__ outb, float* __restrict__ outf) {
  __shared__ u16 lds[2*24576];   // per buf: X (8192 u16) | W (16384 u16); 96 KB total
  const int tid  = threadIdx.x;
  const int wave = tid >> 6, lane = tid & 63;
  const int wm = wave >> 2, wn = wave & 3;
  const int lr = lane & 15, g = lane >> 4;

  // bijective XCD swizzle (grid % 8 == 0), n-fastest within each XCD chunk
  const int NY  = (MODE == 0) ? 12 : 4;
  const int q   = (int)gridDim.x >> 3;
  const int bid = (int)blockIdx.x;
  const int nf_ = (bid & 7) * q + (bid >> 3);
  const int m0  = (nf_ / NY) * 128;
  const int ngl = (nf_ % NY) * 256;   // row into Wt (0..3071 / 0..1023)

  // prologue: stage tiles 0 (buf0) and 1 (buf1); wait tile 0, keep tile 1 in flight
  STAGE6(0, lds);
  STAGE6(1, lds + 24576);
  asm volatile("s_waitcnt vmcnt(6)" ::: "memory");
  asm volatile("s_barrier" ::: "memory");

  facc4 acc[4][4] = {};              // [nf][mf]
  bfrag8 xa[4], wa[4], xb[4], wb[4]; // set A (kh0-slot), set B (kh1-slot)

  RD8(xa, wa, lds, 0);               // (tile 0, kh0)

  #pragma unroll 2
  for (int t = 0; t < NT; ++t) {
    u16* bufp = lds + (t & 1) * 24576;
    u16* bufq = lds + ((t + 1) & 1) * 24576;
    // ---- P0(t): MFMA set A; read set B = (t, kh1) from buf p ----
    asm volatile("s_waitcnt lgkmcnt(0)" ::: "memory"); SBAR0();
    RD8(xb, wb, bufp, 1);
    SBAR0();
    MM16(xa, wa);
    SBAR0();
    asm volatile("s_waitcnt vmcnt(0)" ::: "memory");   // drain t+1's stages (issued P1(t-1))
    asm volatile("s_barrier" ::: "memory");
    // ---- P1(t): MFMA set B; stage t+2 -> buf p; read set A = (t+1, kh0) from buf q ----
    asm volatile("s_waitcnt lgkmcnt(0)" ::: "memory"); SBAR0();
    if (t + 2 < NT) STAGE6(t + 2, bufp);
    if (t + 1 < NT) RD8(xa, wa, bufq, 0);
    SBAR0();
    MM16(xb, wb);
    SBAR0();
    asm volatile("s_barrier" ::: "memory");
  }

  // ---- epilogue: lane (lr,g) reg r = out[m = ..+lr][col = ..+g*4+r]
  const int sel = (MODE == 0) ? (ngl >> 10) : 0;
  const bool doElu = (MODE == 0) && (sel < 2);
  const int coly = (MODE == 0) ? (ngl & 1023) : ngl;
  #pragma unroll
  for (int nf = 0; nf < 4; ++nf) {
    #pragma unroll
    for (int mf = 0; mf < 4; ++mf) {
      const facc4 a = acc[nf][mf];
      const int m = m0 + wm*64 + mf*16 + lr;
      const int col0 = coly + wn*64 + nf*16 + g*4;
      float v0 = a[0], v1 = a[1], v2 = a[2], v3 = a[3];
      if (MODE == 0) {
        if (doElu) {
          v0 = (v0 > 0.f) ? (v0 + 1.f) : __expf(v0);
          v1 = (v1 > 0.f) ? (v1 + 1.f) : __expf(v1);
          v2 = (v2 > 0.f) ? (v2 + 1.f) : __expf(v2);
          v3 = (v3 > 0.f) ? (v3 + 1.f) : __expf(v3);
        }
        uint2 pk;
        pk.x = (u32)f2bf(v0) | ((u32)f2bf(v1) << 16);
        pk.y = (u32)f2bf(v2) | ((u32)f2bf(v3) << 16);
        *(uint2*)&outb[(size_t)sel*((size_t)MROWS*DIM) + (size_t)m*DIM + col0] = pk;
      } else {
        float4 pk; pk.x = v0; pk.y = v1; pk.z = v2; pk.w = v3;
        *(float4*)&outf[(size_t)m*DIM + col0] = pk;
      }
    }
  }
}

// ---------------- chunked causal linear-attention scan (MFMA) ----------------
// Ast layout: per (bh, chunk), 64x64 bf16 [e][d] = (K^T V)^T

__global__ __launch_bounds__(256) void phaseA(const u16* __restrict__ Kb, const u16* __restrict__ Vb,
                                              u16* __restrict__ Ast, float* __restrict__ ksum) {
  const int c = blockIdx.x, bh = blockIdx.y;
  const int b = bh >> 4, h = bh & 15;
  const int tid = threadIdx.x;
  const int wave = tid >> 6, lane = tid & 63, lr = lane & 15, g = lane >> 4;
  __shared__ u16 lKt[64*TS];   // lKt[d][t] = K[t][d]
  __shared__ u16 lVt[64*TS];   // lVt[e][t] = V[t][e]
  const size_t mbase = (size_t)b*SEQ + (size_t)c*CHUNK;

  for (int s = tid; s < 512; s += 256) {
    const int t = s >> 3, dg = (s & 7) * 8;
    const bfrag8 kk = *(const bfrag8*)&Kb[(mbase + t)*DIM + h*64 + dg];
    const bfrag8 vv = *(const bfrag8*)&Vb[(mbase + t)*DIM + h*64 + dg];
    #pragma unroll
    for (int j = 0; j < 8; ++j) {
      lKt[(dg + j)*TS + t] = (u16)kk[j];
      lVt[(dg + j)*TS + t] = (u16)vv[j];
    }
  }
  __syncthreads();

  facc4 acc[4] = {};
  #pragma unroll
  for (int kt = 0; kt < 2; ++kt) {
    const bfrag8 af = *(const bfrag8*)&lVt[(wave*16 + lr)*TS + kt*32 + g*8];
    #pragma unroll
    for (int j = 0; j < 4; ++j) {
      const bfrag8 bk = *(const bfrag8*)&lKt[(j*16 + lr)*TS + kt*32 + g*8];
      acc[j] = __builtin_amdgcn_mfma_f32_16x16x32_bf16(af, bk, acc[j], 0, 0, 0);
    }
  }
  u16* dst = Ast + (((size_t)bh*NCHUNK + c) << 12);
  #pragma unroll
  for (int j = 0; j < 4; ++j)
    #pragma unroll
    for (int r = 0; r < 4; ++r)
      dst[(wave*16 + g*4 + r)*64 + j*16 + lr] = f2bf(acc[j][r]);

  const int d = tid >> 2, seg = tid & 3;
  const bfrag8 k0 = *(const bfrag8*)&lKt[d*TS + seg*16];
  const bfrag8 k1 = *(const bfrag8*)&lKt[d*TS + seg*16 + 8];
  float s = 0.f;
  #pragma unroll
  for (int j = 0; j < 8; ++j) s += bf2f((u16)k0[j]) + bf2f((u16)k1[j]);
  s += __shfl_xor(s, 1, 64);
  s += __shfl_xor(s, 2, 64);
  if (seg == 0) ksum[((size_t)bh*NCHUNK + c)*64 + d] = s;
}

__global__ __launch_bounds__(256) void phaseB(u16* __restrict__ Ast, float* __restrict__ ksum) {
  const int bh = blockIdx.x, slice = blockIdx.y;
  const int tid = threadIdx.x;
  u16* base = Ast + (size_t)bh*NCHUNK*4096 + slice*256 + tid;
  float v[NCHUNK];
  #pragma unroll
  for (int c = 0; c < NCHUNK; ++c) v[c] = bf2f(base[(size_t)c*4096]);
  float run = 0.f;
  #pragma unroll
  for (int c = 0; c < NCHUNK; ++c) { base[(size_t)c*4096] = f2bf(run); run += v[c]; }
  if (slice == 0 && tid < 64) {
    float rs = 0.f;
    float* kp = ksum + (size_t)bh*NCHUNK*64 + tid;
    for (int c = 0; c < NCHUNK; ++c) { const float t = kp[c*64]; kp[c*64] = rs; rs += t; }
  }
}

__global__ __launch_bounds__(256) void phaseC(const u16* __restrict__ Qb, const u16* __restrict__ Kb,
                                              const u16* __restrict__ Vb, const u16* __restrict__ Ast,
                                              const float* __restrict__ ksum, u16* __restrict__ Ob) {
  const int c = blockIdx.x, bh = blockIdx.y;
  const int b = bh >> 4, h = bh & 15;
  const int tid = threadIdx.x;
  const int wave = tid >> 6, lane = tid & 63, lr = lane & 15, g = lane >> 4;
  __shared__ u16 lS  [64*TS];
  __shared__ u16 lVt [64*TS];
  __shared__ u16 lKVt[64*TS];
  __shared__ float lks[64];
  __shared__ float lrs[64];
  __shared__ float lqk[64];
  const size_t mbase = (size_t)b*SEQ + (size_t)c*CHUNK;

  for (int s = tid; s < 512; s += 256) {
    const int t = s >> 3, dg = (s & 7) * 8;
    const bfrag8 vv = *(const bfrag8*)&Vb[(mbase + t)*DIM + h*64 + dg];
    #pragma unroll
    for (int j = 0; j < 8; ++j) lVt[(dg + j)*TS + t] = (u16)vv[j];
  }
  const u16* kvsrc = Ast + (((size_t)bh*NCHUNK + c) << 12);
  for (int s = tid; s < 512; s += 256) {
    const int e = s >> 3, dg = (s & 7) * 8;
    *(bfrag8*)&lKVt[e*TS + dg] = *(const bfrag8*)&kvsrc[e*64 + dg];
  }
  if (tid < 64) lks[tid] = ksum[((size_t)bh*NCHUNK + c)*64 + tid];

  bfrag8 qf[2], kf[4][2];
  {
    const u16* qrow = Qb + (mbase + wave*16 + lr)*DIM + h*64;
    qf[0] = *(const bfrag8*)&qrow[g*8];
    qf[1] = *(const bfrag8*)&qrow[32 + g*8];
  }
  #pragma unroll
  for (int j = 0; j < 4; ++j) {
    const u16* krow = Kb + (mbase + j*16 + lr)*DIM + h*64;
    kf[j][0] = *(const bfrag8*)&krow[g*8];
    kf[j][1] = *(const bfrag8*)&krow[32 + g*8];
  }

  facc4 accs[4] = {};
  #pragma unroll
  for (int kt = 0; kt < 2; ++kt)
    #pragma unroll
    for (int j = 0; j < 4; ++j)
      accs[j] = __builtin_amdgcn_mfma_f32_16x16x32_bf16(qf[kt], kf[j][kt], accs[j], 0, 0, 0);

  float rs[4] = {0.f, 0.f, 0.f, 0.f};
  #pragma unroll
  for (int j = 0; j < 4; ++j) {
    const int cc = j*16 + lr;
    #pragma unroll
    for (int r = 0; r < 4; ++r) {
      const int rr = wave*16 + g*4 + r;
      const float vS = (cc <= rr) ? accs[j][r] : 0.f;
      rs[r] += vS;
      lS[rr*TS + cc] = f2bf(vS);
    }
  }
  #pragma unroll
  for (int r = 0; r < 4; ++r) {
    float t = rs[r];
    t += __shfl_xor(t, 1, 64); t += __shfl_xor(t, 2, 64);
    t += __shfl_xor(t, 4, 64); t += __shfl_xor(t, 8, 64);
    if (lr == 0) lrs[wave*16 + g*4 + r] = t;
  }
  __syncthreads();

  {
    const u16* qr2 = Qb + (mbase + wave*16 + lr)*DIM + h*64 + g*16;
    const bfrag8 a0 = *(const bfrag8*)&qr2[0];
    const bfrag8 a1 = *(const bfrag8*)&qr2[8];
    float t = 0.f;
    #pragma unroll
    for (int j = 0; j < 8; ++j)
      t += bf2f((u16)a0[j]) * lks[g*16 + j] + bf2f((u16)a1[j]) * lks[g*16 + 8 + j];
    t += __shfl_xor(t, 16, 64);
    t += __shfl_xor(t, 32, 64);
    if (g == 0) lqk[wave*16 + lr] = t;
  }

  facc4 acco[4] = {};
  #pragma unroll
  for (int kt = 0; kt < 2; ++kt) {
    const bfrag8 sf = *(const bfrag8*)&lS[(wave*16 + lr)*TS + kt*32 + g*8];
    #pragma unroll
    for (int j = 0; j < 4; ++j) {
      const bfrag8 vf = *(const bfrag8*)&lVt[(j*16 + lr)*TS + kt*32 + g*8];
      acco[j] = __builtin_amdgcn_mfma_f32_16x16x32_bf16(sf, vf, acco[j], 0, 0, 0);
    }
  }
  #pragma unroll
  for (int kt = 0; kt < 2; ++kt)
    #pragma unroll
    for (int j = 0; j < 4; ++j) {
      const bfrag8 kvf = *(const bfrag8*)&lKVt[(j*16 + lr)*TS + kt*32 + g*8];
      acco[j] = __builtin_amdgcn_mfma_f32_16x16x32_bf16(qf[kt], kvf, acco[j], 0, 0, 0);
    }

  #pragma unroll
  for (int r = 0; r < 4; ++r) {
    const int rr = wave*16 + g*4 + r;
    const float rden = 1.0f / (lrs[rr] + lqk[rr] + 1e-6f);
    #pragma unroll
    for (int j = 0; j < 4; ++j)
      Ob[(mbase + rr)*DIM + h*64 + j*16 + lr] = f2bf(acco[j][r] * rden);
  }
}

// ---------------- launch ----------------
extern "C" void kernel_launch(void* const* d_in, const int* in_sizes, int n_in,
                              void* d_out, int out_size, void* d_ws, size_t ws_size,
                              hipStream_t stream) {
  const float* x    = (const float*)d_in[0];
  const float* Wq   = (const float*)d_in[1];
  const float* Wk   = (const float*)d_in[2];
  const float* Wv   = (const float*)d_in[3];
  const float* Wo   = (const float*)d_in[4];
  const float* proj = (const float*)d_in[5];
  float* out = (float*)d_out;

  char* ws = (char*)d_ws;
  u16*   xb   = (u16*)  (ws);                       // 16 MB : x in bf16
  u16*   wt   = (u16*)  (ws + 16777216);            //  8 MB : Wq',Wk',Wv^T,Wo^T bf16 (transposed)
  u16*   qkv  = (u16*)  (ws + 25165824);            // 48 MB : Q,K,V bf16 (post feature map)
  u16*   Ob   = (u16*)  (ws + 75497472);            // 16 MB : attention out bf16
  u16*   Ast  = (u16*)  (ws + 92274688);            // 16 MB : chunk KV states bf16 [e][d]
  float* ksum = (float*)(ws + 109051904);           // 512 KB : chunk k-sums fp32
  (void)ws_size; (void)in_sizes; (void)n_in; (void)out_size;

  conv_f32_bf16<<<dim3((MROWS*DIM)/1024), 256, 0, stream>>>(x, xb);
  fold_qk      <<<dim3(DIM/32, NH, 2), 256, 0, stream>>>(Wq, Wk, proj, wt);
  trans_conv   <<<dim3(DIM/32, DIM/32, 2), 256, 0, stream>>>(Wv, Wo, wt);

  // QKV fused: M=8192, N=3072 (wt rows 0..3071 = Wq'|Wk'|Wv^T); 768 blocks = 3 exact rounds
  gemmK<0><<<dim3(64*12), 512, 0, stream>>>(xb, wt, qkv, nullptr);

  const u16* Qb = qkv;
  const u16* Kb = qkv + (size_t)MROWS*DIM;
  const u16* Vb = qkv + 2*(size_t)MROWS*DIM;

  phaseA<<<dim3(NCHUNK, BH), 256, 0, stream>>>(Kb, Vb, Ast, ksum);
  phaseB<<<dim3(BH, 16), 256, 0, stream>>>(Ast, ksum);
  phaseC<<<dim3(NCHUNK, BH), 256, 0, stream>>>(Qb, Kb, Vb, Ast, ksum, Ob);

  // out GEMM: M=8192, N=1024; 256 blocks = 1 exact round
  gemmK<1><<<dim3(64*4), 512, 0, stream>>>(Ob, wt + 3*(size_t)DIM*DIM, nullptr, out);
}